// Round 1
// baseline (9016.816 us; speedup 1.0000x reference)
//
#include <hip/hip_runtime.h>
#include <math.h>

#define DD 35
#define TT 140
#define DHX 70

__device__ __forceinline__ float sigf(float x){ return 1.0f/(1.0f+expf(-x)); }

// ---------------- init ----------------
__global__ void k_init(float* degp, float* degl, int* cnt, int* bstart, int* bend,
                       float* out, const float* b2, int N, int B){
  int i = blockIdx.x*blockDim.x + threadIdx.x;
  if (i < N){ degp[i]=1.0f; degl[i]=1.0f; cnt[i]=0; }
  if (i < B){ bstart[i] = 0x7fffffff; bend[i] = 0; out[i] = b2[0]; }
}

// ---------------- degree + CSR count ----------------
__global__ void k_edge_deg(const int* __restrict__ ei, const int* __restrict__ split,
                           float* degp, float* degl, int* cnt, int E){
  int e = blockIdx.x*blockDim.x + threadIdx.x;
  if (e >= E) return;
  int s = ei[e], d = ei[E+e];
  if (split[s]==1) atomicAdd(&degp[d], 1.0f); else atomicAdd(&degl[d], 1.0f);
  atomicAdd(&cnt[d], 1);
}

// deg -> rsqrt in place; batch ranges
__global__ void k_node1(float* degp, float* degl, const int* __restrict__ batch,
                        int* bstart, int* bend, int N){
  int i = blockIdx.x*blockDim.x + threadIdx.x;
  if (i >= N) return;
  degp[i] = rsqrtf(degp[i]);
  degl[i] = rsqrtf(degl[i]);
  int b = batch[i];
  atomicMin(&bstart[b], i);
  atomicMax(&bend[b], i+1);
}

// ---------------- exclusive scan (3 phase), 1024 elems / block ----------------
__global__ void k_scanA(const int* __restrict__ cnt, int* excl, int* bsum, int N){
  __shared__ int sh[256];
  int t = threadIdx.x;
  int base = (blockIdx.x*256 + t)*4;
  int v0 = (base+0<N)? cnt[base+0]:0;
  int v1 = (base+1<N)? cnt[base+1]:0;
  int v2 = (base+2<N)? cnt[base+2]:0;
  int v3 = (base+3<N)? cnt[base+3]:0;
  int s = v0+v1+v2+v3;
  sh[t] = s; __syncthreads();
  for (int o=1;o<256;o<<=1){
    int add = (t>=o)? sh[t-o] : 0; __syncthreads();
    sh[t] += add; __syncthreads();
  }
  int incl = sh[t];
  int ex = incl - s;
  if (t==255) bsum[blockIdx.x] = incl;
  if (base+0<N) excl[base+0]=ex;
  if (base+1<N) excl[base+1]=ex+v0;
  if (base+2<N) excl[base+2]=ex+v0+v1;
  if (base+3<N) excl[base+3]=ex+v0+v1+v2;
}

__global__ void k_scanB(int* bsum, int nb){
  __shared__ int sh[512];
  int t = threadIdx.x;
  int s = (t<nb)? bsum[t] : 0;
  sh[t]=s; __syncthreads();
  for (int o=1;o<512;o<<=1){
    int add=(t>=o)?sh[t-o]:0; __syncthreads();
    sh[t]+=add; __syncthreads();
  }
  if (t<nb) bsum[t] = sh[t]-s;
}

__global__ void k_scanC(int* rowptr, int* cursor, const int* __restrict__ bsum, int N, int E){
  int i = blockIdx.x*blockDim.x + threadIdx.x;
  if (i<N){ int v = rowptr[i] + bsum[i>>10]; rowptr[i]=v; cursor[i]=v; }
  if (i==0) rowptr[N] = E;
}

// ---------------- fill CSR ----------------
__global__ void k_fill(const int* __restrict__ ei, const int* __restrict__ split,
                       const float* __restrict__ dinvp, const float* __restrict__ dinvl,
                       int* cursor, int* col, float* coef, int E){
  int e = blockIdx.x*blockDim.x + threadIdx.x;
  if (e >= E) return;
  int s = ei[e], d = ei[E+e];
  int pos = atomicAdd(&cursor[d], 1);
  col[pos] = s;
  float c = (split[s]==1) ? (dinvp[s]*dinvp[d]) : -(dinvl[s]*dinvl[d]);
  coef[pos] = c;
}

// ---------------- fused GCN layer (both stacks), wave per node ----------------
__global__ void __launch_bounds__(256)
k_gcn(const float* __restrict__ hp, const float* __restrict__ hl,
      float* __restrict__ hpo, float* __restrict__ hlo,
      const int* __restrict__ rowptr, const int* __restrict__ col, const float* __restrict__ coef,
      const float* __restrict__ dinvp, const float* __restrict__ dinvl,
      const float* __restrict__ Wp, const float* __restrict__ bp,
      const float* __restrict__ Wl, const float* __restrict__ bl, int N){
  int node = blockIdx.x*4 + (threadIdx.x>>6);
  if (node >= N) return;
  int lane = threadIdx.x & 63;
  bool act = lane < DD;
  int c = lane;
  int e0 = rowptr[node], e1 = rowptr[node+1];
  float accp = 0.f, accl = 0.f;
  for (int e=e0; e<e1; ++e){
    int s = col[e]; float cf = coef[e];
    if (cf > 0.f){ if (act) accp += cf * hp[s*DD+c]; }
    else        { if (act) accl -= cf * hl[s*DD+c]; }
  }
  float dp = dinvp[node], dl = dinvl[node];
  float zp = accp, zl = accl;
  if (act){
    zp += hp[node*DD+c]*dp*dp;
    zl += hl[node*DD+c]*dl*dl;
  }
  float op=0.f, ol=0.f;
  for (int j=0;j<DD;++j){
    float zpj = __shfl(zp, j, 64);
    float zlj = __shfl(zl, j, 64);
    if (act){ op += zpj*Wp[j*DD+c]; ol += zlj*Wl[j*DD+c]; }
  }
  if (act){
    hpo[node*DD+c] = fmaxf(op + bp[c], 0.f);
    hlo[node*DD+c] = fmaxf(ol + bl[c], 0.f);
  }
}

// ---------------- batch pooling ----------------
__global__ void k_bsum(const float* __restrict__ hp, const float* __restrict__ hl,
                       const int* __restrict__ bstart, const int* __restrict__ bend,
                       float* pro, float* lig){
  __shared__ float sp[4][DD], sl[4][DD];
  int b = blockIdx.x;
  int w = threadIdx.x>>6, lane = threadIdx.x&63;
  int s0 = bstart[b], s1 = bend[b];
  float ap=0.f, al=0.f;
  if (lane < DD && s0 < s1){
    for (int n=s0+w; n<s1; n+=4){ ap += hp[n*DD+lane]; al += hl[n*DD+lane]; }
  }
  if (lane < DD){ sp[w][lane]=ap; sl[w][lane]=al; }
  __syncthreads();
  if (threadIdx.x < DD){
    int d = threadIdx.x;
    pro[b*DD+d] = sp[0][d]+sp[1][d]+sp[2][d]+sp[3][d];
    lig[b*DD+d] = sl[0][d]+sl[1][d]+sl[2][d]+sl[3][d];
  }
}

// ---------------- reverse LSTM common chain (zero inputs, steps t=139..2) -------
__global__ void k_lstm_common(const float* __restrict__ wib, const float* __restrict__ whb,
                              const float* __restrict__ bib, const float* __restrict__ bhb,
                              float* hbc, float* hbcst){
  __shared__ float h[DD], cc[DD], g[4*DD];
  int t = threadIdx.x;
  if (t < DD){ h[t]=0.f; cc[t]=0.f; }
  __syncthreads();
  for (int k=1;k<=TT-2;++k){
    if (t < 4*DD){
      float acc = bib[t]+bhb[t];
      for (int m=0;m<DD;++m) acc += whb[t*DD+m]*h[m];
      g[t]=acc;
    }
    __syncthreads();
    if (t < DD){
      float ig=g[t], fg=g[DD+t], gg=g[2*DD+t], og=g[3*DD+t];
      float cv = sigf(fg)*cc[t] + sigf(ig)*tanhf(gg);
      float hv = sigf(og)*tanhf(cv);
      cc[t]=cv; h[t]=hv;
      hbc[(TT-k)*DD + t] = hv;
    }
    __syncthreads();
  }
  if (t<DD){ hbcst[t]=h[t]; hbcst[DD+t]=cc[t]; }
}

// ---------------- per-batch LSTM: fwd 140 steps + bwd 2-step tail ---------------
__global__ void k_lstm_batch(const float* __restrict__ lig, const float* __restrict__ pro,
   const float* __restrict__ wif, const float* __restrict__ whf,
   const float* __restrict__ bif, const float* __restrict__ bhf,
   const float* __restrict__ wib, const float* __restrict__ whb,
   const float* __restrict__ bib, const float* __restrict__ bhb,
   const float* __restrict__ hbc, const float* __restrict__ hbcst, float* outseq){
  __shared__ float x0[DD], x1[DD], h[DD], cc[DD], g[4*DD], xg0[4*DD], xg1[4*DD];
  int b = blockIdx.x, t = threadIdx.x;
  if (t<DD){ x0[t]=lig[b*DD+t]; x1[t]=pro[b*DD+t]; h[t]=0.f; cc[t]=0.f; }
  __syncthreads();
  if (t<4*DD){
    float a0=0.f, a1=0.f;
    for (int m=0;m<DD;++m){ a0 += wif[t*DD+m]*x0[m]; a1 += wif[t*DD+m]*x1[m]; }
    xg0[t]=a0; xg1[t]=a1;
  }
  __syncthreads();
  float* outb = outseq + (size_t)b*TT*DHX;
  for (int tt=0;tt<TT;++tt){
    if (t<4*DD){
      float acc = bif[t]+bhf[t] + (tt==0? xg0[t] : (tt==1? xg1[t] : 0.f));
      for (int m=0;m<DD;++m) acc += whf[t*DD+m]*h[m];
      g[t]=acc;
    }
    __syncthreads();
    if (t<DD){
      float ig=g[t], fg=g[DD+t], gg=g[2*DD+t], og=g[3*DD+t];
      float cv = sigf(fg)*cc[t]+sigf(ig)*tanhf(gg);
      float hv = sigf(og)*tanhf(cv);
      cc[t]=cv; h[t]=hv;
      outb[tt*DHX + t] = hv;
    }
    __syncthreads();
  }
  // backward tail: input projections with wib, restore common chain state
  if (t<4*DD){
    float a0=0.f, a1=0.f;
    for (int m=0;m<DD;++m){ a0 += wib[t*DD+m]*x0[m]; a1 += wib[t*DD+m]*x1[m]; }
    xg0[t]=a0; xg1[t]=a1;
  }
  if (t<DD){ h[t]=hbcst[t]; cc[t]=hbcst[DD+t]; }
  __syncthreads();
  for (int step=0; step<2; ++step){
    int tt = 1-step;  // process t=1 (pro) then t=0 (lig)
    if (t<4*DD){
      float acc = bib[t]+bhb[t] + (tt==1? xg1[t] : xg0[t]);
      for (int m=0;m<DD;++m) acc += whb[t*DD+m]*h[m];
      g[t]=acc;
    }
    __syncthreads();
    if (t<DD){
      float ig=g[t], fg=g[DD+t], gg=g[2*DD+t], og=g[3*DD+t];
      float cv = sigf(fg)*cc[t]+sigf(ig)*tanhf(gg);
      float hv = sigf(og)*tanhf(cv);
      cc[t]=cv; h[t]=hv;
      outb[tt*DHX + DD + t] = hv;
    }
    __syncthreads();
  }
  for (int idx=t; idx<(TT-2)*DD; idx+=blockDim.x){
    int tt = 2 + idx/DD, d = idx%DD;
    outb[tt*DHX + DD + d] = hbc[tt*DD + d];
  }
}

// ---------------- attention (mask-collapsed) per batch ----------------
__global__ void __launch_bounds__(256)
k_attn(const float* __restrict__ outseq,
  const float* __restrict__ Wq, const float* __restrict__ bq,
  const float* __restrict__ Wk, const float* __restrict__ bk,
  const float* __restrict__ Wv, const float* __restrict__ bv,
  const float* __restrict__ Wo, const float* __restrict__ bo,
  float* PT, int B){
  __shared__ float so[TT*DHX];
  __shared__ float sk[TT*DHX];
  __shared__ float sv[TT*DHX];
  __shared__ float sq[2*DHX];
  __shared__ float es[TT];
  __shared__ float red[4];
  __shared__ float ctx[3*DHX];
  int b = blockIdx.x, tid = threadIdx.x;
  const float* ob = outseq + (size_t)b*TT*DHX;
  for (int i=tid;i<TT*DHX;i+=256) so[i]=ob[i];
  __syncthreads();
  for (int i=tid;i<TT*DHX;i+=256){
    int s=i/DHX, d=i%DHX;
    float ak=bk[d], av=bv[d];
    const float* r = so + s*DHX;
    for (int j=0;j<DHX;++j){ float o=r[j]; ak += o*Wk[d*DHX+j]; av += o*Wv[d*DHX+j]; }
    sk[i]=ak; sv[i]=av;
  }
  for (int i=tid;i<2*DHX;i+=256){
    int s=i/DHX, d=i%DHX;
    float a=bq[d];
    for (int j=0;j<DHX;++j) a += so[s*DHX+j]*Wq[d*DHX+j];
    sq[i]=a;
  }
  __syncthreads();
  const float scale = 0.11952286093343936f; // 1/sqrt(70)
  for (int s=tid;s<TT;s+=256){
    float a=0.f;
    for (int j=0;j<DHX;++j) a += sq[DHX+j]*sk[s*DHX+j];
    es[s] = a*scale;
  }
  __syncthreads();
  if (tid < 64){
    float m=-1e30f;
    for (int s=tid;s<TT;s+=64) if (s!=1) m=fmaxf(m, es[s]);
    for (int o=32;o;o>>=1) m = fmaxf(m, __shfl_xor(m,o,64));
    if (tid==0) red[0]=m;
  }
  __syncthreads();
  float m = red[0];
  for (int s=tid;s<TT;s+=256) es[s] = (s==1)? 0.f : expf(es[s]-m);
  __syncthreads();
  if (tid<64){
    float sum=0.f;
    for (int s=tid;s<TT;s+=64) sum+=es[s];
    for (int o=32;o;o>>=1) sum += __shfl_xor(sum,o,64);
    if (tid==0) red[1]=sum;
  }
  if (tid==0){
    float s00=0.f,s01=0.f;
    for (int j=0;j<DHX;++j){ s00 += sq[j]*sk[j]; s01 += sq[j]*sk[DHX+j]; }
    s00*=scale; s01*=scale;
    float mm=fmaxf(s00,s01);
    float e0=expf(s00-mm), e1=expf(s01-mm);
    red[2]=e0/(e0+e1); red[3]=e1/(e0+e1);
  }
  __syncthreads();
  float inv = 1.0f/red[1];
  float a0=red[2], a1=red[3];
  if (tid < DHX){
    int d=tid;
    float c1=0.f;
    for (int s=0;s<TT;++s) c1 += es[s]*sv[s*DHX+d];
    ctx[DHX+d] = c1*inv;
    ctx[d] = a0*sv[d] + a1*sv[DHX+d];
    ctx[2*DHX+d] = sv[DHX+d];
  }
  __syncthreads();
  for (int i=tid;i<3*DHX;i+=256){
    int tt=i/DHX, d=i%DHX;
    float a=bo[d];
    const float* cv = ctx + tt*DHX;
    for (int j=0;j<DHX;++j) a += Wo[d*DHX+j]*cv[j];
    PT[(size_t)i*B + b] = a;
  }
}

// ---------------- W1 tail-block sum (cols 140..9799 collapse onto p2) ----------
__global__ void k_w1s(const float* __restrict__ W1, float* w1s){
  int j = blockIdx.x; int d = threadIdx.x;
  if (d >= DHX) return;
  const float* r = W1 + (size_t)j*(TT*DHX);
  float acc=0.f;
  for (int t=2;t<TT;++t) acc += r[t*DHX+d];
  w1s[(size_t)j*DHX+d]=acc;
}

// ---------------- y = P @ [W1a|W1b|W1s]^T + b1 (transposed out) ----------------
__global__ void k_y(const float* __restrict__ PT, const float* __restrict__ W1,
                    const float* __restrict__ w1s, const float* __restrict__ b1,
                    float* yT, int B){
  int j = blockIdx.x; int b = threadIdx.x;
  const float* r = W1 + (size_t)j*(TT*DHX);
  float acc = b1[j];
  for (int i=0;i<2*DHX;++i) acc += r[i]*PT[(size_t)i*B+b];
  const float* rs = w1s + (size_t)j*DHX;
  for (int i=0;i<DHX;++i) acc += rs[i]*PT[(size_t)(2*DHX+i)*B+b];
  yT[(size_t)j*B+b] = acc;
}

// ---------------- BatchNorm(train) + Mish + W2 reduce ----------------
__global__ void k_bn(const float* __restrict__ yT, const float* __restrict__ gamma,
                     const float* __restrict__ beta, const float* __restrict__ W2,
                     float* out, int B, int J){
  __shared__ float red_s[2];
  int b = threadIdx.x;
  int lane = b & 63, w = b>>6;
  float acc = 0.f;
  int j0 = blockIdx.x*32;
  float invB = 1.0f/(float)B;
  for (int jj=0;jj<32;++jj){
    int j = j0+jj; if (j>=J) break;
    float v = yT[(size_t)j*B + b];
    float s=v;
    for (int o=32;o;o>>=1) s += __shfl_xor(s,o,64);
    if (lane==0) red_s[w]=s;
    __syncthreads();
    float mu = (red_s[0]+red_s[1]) * invB;
    __syncthreads();
    float dd = v-mu;
    float q=dd*dd;
    for (int o=32;o;o>>=1) q += __shfl_xor(q,o,64);
    if (lane==0) red_s[w]=q;
    __syncthreads();
    float var = (red_s[0]+red_s[1]) * invB;
    __syncthreads();
    float xn = dd*rsqrtf(var+1e-5f)*gamma[j]+beta[j];
    float sp = (xn>20.f)? xn : log1pf(expf(xn));
    float mish = xn*tanhf(sp);
    acc += mish*W2[j];
  }
  atomicAdd(&out[b], acc);
}

extern "C" void kernel_launch(void* const* d_in, const int* in_sizes, int n_in,
                              void* d_out, int out_size, void* d_ws, size_t ws_size,
                              hipStream_t stream)
{
  const float* x    = (const float*)d_in[0];
  const int*   ei   = (const int*)  d_in[1];
  const int*   split= (const int*)  d_in[2];
  const int*   batch= (const int*)  d_in[3];
  const float* Wp   = (const float*)d_in[4];
  const float* bp   = (const float*)d_in[5];
  const float* Wl   = (const float*)d_in[6];
  const float* bl   = (const float*)d_in[7];
  const float* wif  = (const float*)d_in[8];
  const float* whf  = (const float*)d_in[9];
  const float* bif  = (const float*)d_in[10];
  const float* bhf  = (const float*)d_in[11];
  const float* wib  = (const float*)d_in[12];
  const float* whb  = (const float*)d_in[13];
  const float* bib  = (const float*)d_in[14];
  const float* bhb  = (const float*)d_in[15];
  const float* Wq   = (const float*)d_in[16];
  const float* bq   = (const float*)d_in[17];
  const float* Wk   = (const float*)d_in[18];
  const float* bk   = (const float*)d_in[19];
  const float* Wv   = (const float*)d_in[20];
  const float* bv   = (const float*)d_in[21];
  const float* Wo   = (const float*)d_in[22];
  const float* bo   = (const float*)d_in[23];
  const float* W1   = (const float*)d_in[24];
  const float* b1   = (const float*)d_in[25];
  const float* gam  = (const float*)d_in[26];
  const float* bet  = (const float*)d_in[27];
  const float* W2   = (const float*)d_in[28];
  const float* b2   = (const float*)d_in[29];
  float* out = (float*)d_out;

  const int N = in_sizes[0]/DD;
  const int E = in_sizes[1]/2;
  const int B = out_size;
  const int J = in_sizes[25];
  (void)n_in; (void)ws_size;

  char* ws = (char*)d_ws;
  size_t off = 0;
  auto carve = [&](size_t bytes)->void*{ void* p = ws + off; off = (off + bytes + 255) & ~(size_t)255; return p; };
  float* hpA   = (float*)carve((size_t)N*DD*4);
  float* hlA   = (float*)carve((size_t)N*DD*4);
  float* hpB   = (float*)carve((size_t)N*DD*4);
  float* hlB   = (float*)carve((size_t)N*DD*4);
  float* dinvp = (float*)carve((size_t)N*4);
  float* dinvl = (float*)carve((size_t)N*4);
  int*   cnt   = (int*)  carve((size_t)N*4);
  int*   rowptr= (int*)  carve((size_t)(N+1)*4);
  int*   cursor= (int*)  carve((size_t)N*4);
  int*   bsum  = (int*)  carve(4096);
  int*   col   = (int*)  carve((size_t)E*4);
  float* coef  = (float*)carve((size_t)E*4);
  float* pro   = (float*)carve((size_t)B*DD*4);
  float* lig   = (float*)carve((size_t)B*DD*4);
  int*   bstart= (int*)  carve((size_t)B*4);
  int*   bend  = (int*)  carve((size_t)B*4);
  float* hbc   = (float*)carve((size_t)TT*DD*4);
  float* hbcst = (float*)carve(2*DD*4);
  float* outseq= (float*)carve((size_t)B*TT*DHX*4);
  float* PT    = (float*)carve((size_t)3*DHX*B*4);
  float* w1s   = (float*)carve((size_t)J*DHX*4);
  float* yT    = (float*)carve((size_t)J*B*4);

  int mx = (N>B)?N:B;
  k_init<<<(mx+255)/256, 256, 0, stream>>>(dinvp, dinvl, cnt, bstart, bend, out, b2, N, B);
  k_edge_deg<<<(E+255)/256, 256, 0, stream>>>(ei, split, dinvp, dinvl, cnt, E);
  k_node1<<<(N+255)/256, 256, 0, stream>>>(dinvp, dinvl, batch, bstart, bend, N);
  int n4 = (N+3)/4;
  int nbA = (n4+255)/256;
  k_scanA<<<nbA, 256, 0, stream>>>(cnt, rowptr, bsum, N);
  k_scanB<<<1, 512, 0, stream>>>(bsum, nbA);
  k_scanC<<<(N+255)/256, 256, 0, stream>>>(rowptr, cursor, bsum, N, E);
  k_fill<<<(E+255)/256, 256, 0, stream>>>(ei, split, dinvp, dinvl, cursor, col, coef, E);

  const float* ip = x; const float* il = x;
  float* op_ = hpA; float* ol_ = hlA; float* np_ = hpB; float* nl_ = hlB;
  for (int i=0;i<5;++i){
    k_gcn<<<(N+3)/4, 256, 0, stream>>>(ip, il, op_, ol_, rowptr, col, coef, dinvp, dinvl,
      Wp + (size_t)i*DD*DD, bp + (size_t)i*DD, Wl + (size_t)i*DD*DD, bl + (size_t)i*DD, N);
    ip = op_; il = ol_;
    float* tp = op_; op_ = np_; np_ = tp;
    float* tl = ol_; ol_ = nl_; nl_ = tl;
  }

  k_bsum<<<B, 256, 0, stream>>>(ip, il, bstart, bend, pro, lig);
  k_lstm_common<<<1, 192, 0, stream>>>(wib, whb, bib, bhb, hbc, hbcst);
  k_lstm_batch<<<B, 192, 0, stream>>>(lig, pro, wif, whf, bif, bhf, wib, whb, bib, bhb, hbc, hbcst, outseq);
  k_attn<<<B, 256, 0, stream>>>(outseq, Wq, bq, Wk, bk, Wv, bv, Wo, bo, PT, B);
  k_w1s<<<J, 128, 0, stream>>>(W1, w1s);
  k_y<<<J, B, 0, stream>>>(PT, W1, w1s, b1, yT, B);
  k_bn<<<(J+31)/32, B, 0, stream>>>(yT, gam, bet, W2, out, B, J);
}

// Round 2
// 5536.263 us; speedup vs baseline: 1.6287x; 1.6287x over previous
//
#include <hip/hip_runtime.h>
#include <math.h>

#define DD 35
#define TT 140
#define DHX 70

__device__ __forceinline__ float sigf(float x){ return 1.0f/(1.0f+expf(-x)); }

// ---------------- init ----------------
__global__ void k_init(unsigned int* packed, int* bstart, int* bend,
                       float* out, const float* b2, int N, int B){
  int i = blockIdx.x*blockDim.x + threadIdx.x;
  if (i < N){ packed[i]=0u; }
  if (i < B){ bstart[i] = 0x7fffffff; bend[i] = 0; out[i] = b2[0]; }
}

// ---------------- degree count (packed: hi16=protein, lo16=ligand) ----------
__global__ void k_edge_deg(const int* __restrict__ ei, const int* __restrict__ split,
                           unsigned int* packed, int E){
  int e = blockIdx.x*blockDim.x + threadIdx.x;
  if (e >= E) return;
  int s = ei[e], d = ei[E+e];
  atomicAdd(&packed[d], (split[s]==1) ? 0x10000u : 1u);
}

// unpack degrees -> rsqrt; CSR counts; batch ranges via boundary detection
__global__ void k_node1(const unsigned int* __restrict__ packed,
                        float* dinvp, float* dinvl, int* cnt,
                        const int* __restrict__ batch,
                        int* bstart, int* bend, int N){
  int i = blockIdx.x*blockDim.x + threadIdx.x;
  if (i >= N) return;
  unsigned int p = packed[i];
  int pc = (int)(p >> 16), lc = (int)(p & 0xFFFFu);
  dinvp[i] = rsqrtf((float)(pc + 1));
  dinvl[i] = rsqrtf((float)(lc + 1));
  cnt[i] = pc + lc;
  int b = batch[i];
  if (i == 0 || batch[i-1] != b) bstart[b] = i;
  if (i == N-1 || batch[i+1] != b) bend[b] = i + 1;
}

// ---------------- exclusive scan (3 phase), 1024 elems / block ----------------
__global__ void k_scanA(const int* __restrict__ cnt, int* excl, int* bsum, int N){
  __shared__ int sh[256];
  int t = threadIdx.x;
  int base = (blockIdx.x*256 + t)*4;
  int v0 = (base+0<N)? cnt[base+0]:0;
  int v1 = (base+1<N)? cnt[base+1]:0;
  int v2 = (base+2<N)? cnt[base+2]:0;
  int v3 = (base+3<N)? cnt[base+3]:0;
  int s = v0+v1+v2+v3;
  sh[t] = s; __syncthreads();
  for (int o=1;o<256;o<<=1){
    int add = (t>=o)? sh[t-o] : 0; __syncthreads();
    sh[t] += add; __syncthreads();
  }
  int incl = sh[t];
  int ex = incl - s;
  if (t==255) bsum[blockIdx.x] = incl;
  if (base+0<N) excl[base+0]=ex;
  if (base+1<N) excl[base+1]=ex+v0;
  if (base+2<N) excl[base+2]=ex+v0+v1;
  if (base+3<N) excl[base+3]=ex+v0+v1+v2;
}

__global__ void k_scanB(int* bsum, int nb){
  __shared__ int sh[512];
  int t = threadIdx.x;
  int s = (t<nb)? bsum[t] : 0;
  sh[t]=s; __syncthreads();
  for (int o=1;o<512;o<<=1){
    int add=(t>=o)?sh[t-o]:0; __syncthreads();
    sh[t]+=add; __syncthreads();
  }
  if (t<nb) bsum[t] = sh[t]-s;
}

__global__ void k_scanC(int* rowptr, int* cursor, const int* __restrict__ bsum, int N, int E){
  int i = blockIdx.x*blockDim.x + threadIdx.x;
  if (i<N){ int v = rowptr[i] + bsum[i>>10]; rowptr[i]=v; cursor[i]=v; }
  if (i==0) rowptr[N] = E;
}

// ---------------- fill CSR ----------------
__global__ void k_fill(const int* __restrict__ ei, const int* __restrict__ split,
                       const float* __restrict__ dinvp, const float* __restrict__ dinvl,
                       int* cursor, int* col, float* coef, int E){
  int e = blockIdx.x*blockDim.x + threadIdx.x;
  if (e >= E) return;
  int s = ei[e], d = ei[E+e];
  int pos = atomicAdd(&cursor[d], 1);
  col[pos] = s;
  float c = (split[s]==1) ? (dinvp[s]*dinvp[d]) : -(dinvl[s]*dinvl[d]);
  coef[pos] = c;
}

// ---------------- fused GCN layer (both stacks), wave per node ----------------
__global__ void __launch_bounds__(256)
k_gcn(const float* __restrict__ hp, const float* __restrict__ hl,
      float* __restrict__ hpo, float* __restrict__ hlo,
      const int* __restrict__ rowptr, const int* __restrict__ col, const float* __restrict__ coef,
      const float* __restrict__ dinvp, const float* __restrict__ dinvl,
      const float* __restrict__ Wp, const float* __restrict__ bp,
      const float* __restrict__ Wl, const float* __restrict__ bl, int N){
  int node = blockIdx.x*4 + (threadIdx.x>>6);
  if (node >= N) return;
  int ln = threadIdx.x & 63;
  bool act = ln < DD;
  int e0 = rowptr[node], e1 = rowptr[node+1];
  float accp = 0.f, accl = 0.f;
  int e = e0;
  // unroll-4: 4 independent gathers in flight
  for (; e+4 <= e1; e+=4){
    int s0=col[e+0], s1=col[e+1], s2=col[e+2], s3=col[e+3];
    float c0=coef[e+0], c1=coef[e+1], c2=coef[e+2], c3=coef[e+3];
    const float* p0 = (c0>0.f? hp: hl) + (size_t)s0*DD;
    const float* p1 = (c1>0.f? hp: hl) + (size_t)s1*DD;
    const float* p2 = (c2>0.f? hp: hl) + (size_t)s2*DD;
    const float* p3 = (c3>0.f? hp: hl) + (size_t)s3*DD;
    if (act){
      float v0=p0[ln], v1=p1[ln], v2=p2[ln], v3=p3[ln];
      accp += fmaxf(c0,0.f)*v0 + fmaxf(c1,0.f)*v1 + fmaxf(c2,0.f)*v2 + fmaxf(c3,0.f)*v3;
      accl += fmaxf(-c0,0.f)*v0 + fmaxf(-c1,0.f)*v1 + fmaxf(-c2,0.f)*v2 + fmaxf(-c3,0.f)*v3;
    }
  }
  for (; e < e1; ++e){
    int s = col[e]; float cf = coef[e];
    const float* p = (cf>0.f? hp: hl) + (size_t)s*DD;
    if (act){
      float v = p[ln];
      accp += fmaxf(cf,0.f)*v;
      accl += fmaxf(-cf,0.f)*v;
    }
  }
  float dp = dinvp[node], dl = dinvl[node];
  float zp = accp, zl = accl;
  if (act){
    zp += hp[(size_t)node*DD+ln]*dp*dp;
    zl += hl[(size_t)node*DD+ln]*dl*dl;
  }
  float op=0.f, ol=0.f;
  for (int j=0;j<DD;++j){
    float zpj = __shfl(zp, j, 64);
    float zlj = __shfl(zl, j, 64);
    if (act){ op += zpj*Wp[j*DD+ln]; ol += zlj*Wl[j*DD+ln]; }
  }
  if (act){
    hpo[(size_t)node*DD+ln] = fmaxf(op + bp[ln], 0.f);
    hlo[(size_t)node*DD+ln] = fmaxf(ol + bl[ln], 0.f);
  }
}

// ---------------- batch pooling ----------------
__global__ void k_bsum(const float* __restrict__ hp, const float* __restrict__ hl,
                       const int* __restrict__ bstart, const int* __restrict__ bend,
                       float* pro, float* lig){
  __shared__ float sp[4][DD], sl[4][DD];
  int b = blockIdx.x;
  int w = threadIdx.x>>6, lane = threadIdx.x&63;
  int s0 = bstart[b], s1 = bend[b];
  float ap=0.f, al=0.f;
  if (lane < DD && s0 < s1){
    for (int n=s0+w; n<s1; n+=4){ ap += hp[(size_t)n*DD+lane]; al += hl[(size_t)n*DD+lane]; }
  }
  if (lane < DD){ sp[w][lane]=ap; sl[w][lane]=al; }
  __syncthreads();
  if (threadIdx.x < DD){
    int d = threadIdx.x;
    pro[b*DD+d] = sp[0][d]+sp[1][d]+sp[2][d]+sp[3][d];
    lig[b*DD+d] = sl[0][d]+sl[1][d]+sl[2][d]+sl[3][d];
  }
}

// ---------------- reverse LSTM common chain (zero inputs, steps t=139..2) -------
__global__ void k_lstm_common(const float* __restrict__ wib, const float* __restrict__ whb,
                              const float* __restrict__ bib, const float* __restrict__ bhb,
                              float* hbc, float* hbcst){
  __shared__ float h[DD], cc[DD], g[4*DD];
  int t = threadIdx.x;
  if (t < DD){ h[t]=0.f; cc[t]=0.f; }
  __syncthreads();
  for (int k=1;k<=TT-2;++k){
    if (t < 4*DD){
      float acc = bib[t]+bhb[t];
      for (int m=0;m<DD;++m) acc += whb[t*DD+m]*h[m];
      g[t]=acc;
    }
    __syncthreads();
    if (t < DD){
      float ig=g[t], fg=g[DD+t], gg=g[2*DD+t], og=g[3*DD+t];
      float cv = sigf(fg)*cc[t] + sigf(ig)*tanhf(gg);
      float hv = sigf(og)*tanhf(cv);
      cc[t]=cv; h[t]=hv;
      hbc[(TT-k)*DD + t] = hv;
    }
    __syncthreads();
  }
  if (t<DD){ hbcst[t]=h[t]; hbcst[DD+t]=cc[t]; }
}

// ---------------- per-batch LSTM: fwd 140 steps + bwd 2-step tail ---------------
__global__ void k_lstm_batch(const float* __restrict__ lig, const float* __restrict__ pro,
   const float* __restrict__ wif, const float* __restrict__ whf,
   const float* __restrict__ bif, const float* __restrict__ bhf,
   const float* __restrict__ wib, const float* __restrict__ whb,
   const float* __restrict__ bib, const float* __restrict__ bhb,
   const float* __restrict__ hbc, const float* __restrict__ hbcst, float* outseq){
  __shared__ float x0[DD], x1[DD], h[DD], cc[DD], g[4*DD], xg0[4*DD], xg1[4*DD];
  int b = blockIdx.x, t = threadIdx.x;
  if (t<DD){ x0[t]=lig[b*DD+t]; x1[t]=pro[b*DD+t]; h[t]=0.f; cc[t]=0.f; }
  __syncthreads();
  if (t<4*DD){
    float a0=0.f, a1=0.f;
    for (int m=0;m<DD;++m){ a0 += wif[t*DD+m]*x0[m]; a1 += wif[t*DD+m]*x1[m]; }
    xg0[t]=a0; xg1[t]=a1;
  }
  __syncthreads();
  float* outb = outseq + (size_t)b*TT*DHX;
  for (int tt=0;tt<TT;++tt){
    if (t<4*DD){
      float acc = bif[t]+bhf[t] + (tt==0? xg0[t] : (tt==1? xg1[t] : 0.f));
      for (int m=0;m<DD;++m) acc += whf[t*DD+m]*h[m];
      g[t]=acc;
    }
    __syncthreads();
    if (t<DD){
      float ig=g[t], fg=g[DD+t], gg=g[2*DD+t], og=g[3*DD+t];
      float cv = sigf(fg)*cc[t]+sigf(ig)*tanhf(gg);
      float hv = sigf(og)*tanhf(cv);
      cc[t]=cv; h[t]=hv;
      outb[tt*DHX + t] = hv;
    }
    __syncthreads();
  }
  // backward tail: input projections with wib, restore common chain state
  if (t<4*DD){
    float a0=0.f, a1=0.f;
    for (int m=0;m<DD;++m){ a0 += wib[t*DD+m]*x0[m]; a1 += wib[t*DD+m]*x1[m]; }
    xg0[t]=a0; xg1[t]=a1;
  }
  if (t<DD){ h[t]=hbcst[t]; cc[t]=hbcst[DD+t]; }
  __syncthreads();
  for (int step=0; step<2; ++step){
    int tt = 1-step;  // process t=1 (pro) then t=0 (lig)
    if (t<4*DD){
      float acc = bib[t]+bhb[t] + (tt==1? xg1[t] : xg0[t]);
      for (int m=0;m<DD;++m) acc += whb[t*DD+m]*h[m];
      g[t]=acc;
    }
    __syncthreads();
    if (t<DD){
      float ig=g[t], fg=g[DD+t], gg=g[2*DD+t], og=g[3*DD+t];
      float cv = sigf(fg)*cc[t]+sigf(ig)*tanhf(gg);
      float hv = sigf(og)*tanhf(cv);
      cc[t]=cv; h[t]=hv;
      outb[tt*DHX + DD + t] = hv;
    }
    __syncthreads();
  }
  for (int idx=t; idx<(TT-2)*DD; idx+=blockDim.x){
    int tt = 2 + idx/DD, d = idx%DD;
    outb[tt*DHX + DD + d] = hbc[tt*DD + d];
  }
}

// ---------------- attention (mask-collapsed) per batch ----------------
__global__ void __launch_bounds__(256)
k_attn(const float* __restrict__ outseq,
  const float* __restrict__ Wq, const float* __restrict__ bq,
  const float* __restrict__ Wk, const float* __restrict__ bk,
  const float* __restrict__ Wv, const float* __restrict__ bv,
  const float* __restrict__ Wo, const float* __restrict__ bo,
  float* PT, int B){
  __shared__ float so[TT*DHX];
  __shared__ float sk[TT*DHX];
  __shared__ float sv[TT*DHX];
  __shared__ float sq[2*DHX];
  __shared__ float es[TT];
  __shared__ float red[4];
  __shared__ float ctx[3*DHX];
  int b = blockIdx.x, tid = threadIdx.x;
  const float* ob = outseq + (size_t)b*TT*DHX;
  for (int i=tid;i<TT*DHX;i+=256) so[i]=ob[i];
  __syncthreads();
  for (int i=tid;i<TT*DHX;i+=256){
    int s=i/DHX, d=i%DHX;
    float ak=bk[d], av=bv[d];
    const float* r = so + s*DHX;
    for (int j=0;j<DHX;++j){ float o=r[j]; ak += o*Wk[d*DHX+j]; av += o*Wv[d*DHX+j]; }
    sk[i]=ak; sv[i]=av;
  }
  for (int i=tid;i<2*DHX;i+=256){
    int s=i/DHX, d=i%DHX;
    float a=bq[d];
    for (int j=0;j<DHX;++j) a += so[s*DHX+j]*Wq[d*DHX+j];
    sq[i]=a;
  }
  __syncthreads();
  const float scale = 0.11952286093343936f; // 1/sqrt(70)
  for (int s=tid;s<TT;s+=256){
    float a=0.f;
    for (int j=0;j<DHX;++j) a += sq[DHX+j]*sk[s*DHX+j];
    es[s] = a*scale;
  }
  __syncthreads();
  if (tid < 64){
    float m=-1e30f;
    for (int s=tid;s<TT;s+=64) if (s!=1) m=fmaxf(m, es[s]);
    for (int o=32;o;o>>=1) m = fmaxf(m, __shfl_xor(m,o,64));
    if (tid==0) red[0]=m;
  }
  __syncthreads();
  float m = red[0];
  for (int s=tid;s<TT;s+=256) es[s] = (s==1)? 0.f : expf(es[s]-m);
  __syncthreads();
  if (tid<64){
    float sum=0.f;
    for (int s=tid;s<TT;s+=64) sum+=es[s];
    for (int o=32;o;o>>=1) sum += __shfl_xor(sum,o,64);
    if (tid==0) red[1]=sum;
  }
  if (tid==0){
    float s00=0.f,s01=0.f;
    for (int j=0;j<DHX;++j){ s00 += sq[j]*sk[j]; s01 += sq[j]*sk[DHX+j]; }
    s00*=scale; s01*=scale;
    float mm=fmaxf(s00,s01);
    float e0=expf(s00-mm), e1=expf(s01-mm);
    red[2]=e0/(e0+e1); red[3]=e1/(e0+e1);
  }
  __syncthreads();
  float inv = 1.0f/red[1];
  float a0=red[2], a1=red[3];
  if (tid < DHX){
    int d=tid;
    float c1=0.f;
    for (int s=0;s<TT;++s) c1 += es[s]*sv[s*DHX+d];
    ctx[DHX+d] = c1*inv;
    ctx[d] = a0*sv[d] + a1*sv[DHX+d];
    ctx[2*DHX+d] = sv[DHX+d];
  }
  __syncthreads();
  for (int i=tid;i<3*DHX;i+=256){
    int tt=i/DHX, d=i%DHX;
    float a=bo[d];
    const float* cv = ctx + tt*DHX;
    for (int j=0;j<DHX;++j) a += Wo[d*DHX+j]*cv[j];
    PT[(size_t)i*B + b] = a;
  }
}

// ---------------- W1 tail-block sum (cols 140..9799 collapse onto p2) ----------
__global__ void k_w1s(const float* __restrict__ W1, float* w1s){
  int j = blockIdx.x; int d = threadIdx.x;
  if (d >= DHX) return;
  const float* r = W1 + (size_t)j*(TT*DHX);
  float acc=0.f;
  for (int t=2;t<TT;++t) acc += r[t*DHX+d];
  w1s[(size_t)j*DHX+d]=acc;
}

// ---------------- y = P @ [W1a|W1b|W1s]^T + b1 (transposed out) ----------------
__global__ void k_y(const float* __restrict__ PT, const float* __restrict__ W1,
                    const float* __restrict__ w1s, const float* __restrict__ b1,
                    float* yT, int B){
  int j = blockIdx.x; int b = threadIdx.x;
  const float* r = W1 + (size_t)j*(TT*DHX);
  float acc = b1[j];
  for (int i=0;i<2*DHX;++i) acc += r[i]*PT[(size_t)i*B+b];
  const float* rs = w1s + (size_t)j*DHX;
  for (int i=0;i<DHX;++i) acc += rs[i]*PT[(size_t)(2*DHX+i)*B+b];
  yT[(size_t)j*B+b] = acc;
}

// ---------------- BatchNorm(train) + Mish + W2 reduce ----------------
__global__ void k_bn(const float* __restrict__ yT, const float* __restrict__ gamma,
                     const float* __restrict__ beta, const float* __restrict__ W2,
                     float* out, int B, int J){
  __shared__ float red_s[2];
  int b = threadIdx.x;
  int lane = b & 63, w = b>>6;
  float acc = 0.f;
  int j0 = blockIdx.x*32;
  float invB = 1.0f/(float)B;
  for (int jj=0;jj<32;++jj){
    int j = j0+jj; if (j>=J) break;
    float v = yT[(size_t)j*B + b];
    float s=v;
    for (int o=32;o;o>>=1) s += __shfl_xor(s,o,64);
    if (lane==0) red_s[w]=s;
    __syncthreads();
    float mu = (red_s[0]+red_s[1]) * invB;
    __syncthreads();
    float dd = v-mu;
    float q=dd*dd;
    for (int o=32;o;o>>=1) q += __shfl_xor(q,o,64);
    if (lane==0) red_s[w]=q;
    __syncthreads();
    float var = (red_s[0]+red_s[1]) * invB;
    __syncthreads();
    float xn = dd*rsqrtf(var+1e-5f)*gamma[j]+beta[j];
    float sp = (xn>20.f)? xn : log1pf(expf(xn));
    float mish = xn*tanhf(sp);
    acc += mish*W2[j];
  }
  atomicAdd(&out[b], acc);
}

extern "C" void kernel_launch(void* const* d_in, const int* in_sizes, int n_in,
                              void* d_out, int out_size, void* d_ws, size_t ws_size,
                              hipStream_t stream)
{
  const float* x    = (const float*)d_in[0];
  const int*   ei   = (const int*)  d_in[1];
  const int*   split= (const int*)  d_in[2];
  const int*   batch= (const int*)  d_in[3];
  const float* Wp   = (const float*)d_in[4];
  const float* bp   = (const float*)d_in[5];
  const float* Wl   = (const float*)d_in[6];
  const float* bl   = (const float*)d_in[7];
  const float* wif  = (const float*)d_in[8];
  const float* whf  = (const float*)d_in[9];
  const float* bif  = (const float*)d_in[10];
  const float* bhf  = (const float*)d_in[11];
  const float* wib  = (const float*)d_in[12];
  const float* whb  = (const float*)d_in[13];
  const float* bib  = (const float*)d_in[14];
  const float* bhb  = (const float*)d_in[15];
  const float* Wq   = (const float*)d_in[16];
  const float* bq   = (const float*)d_in[17];
  const float* Wk   = (const float*)d_in[18];
  const float* bk   = (const float*)d_in[19];
  const float* Wv   = (const float*)d_in[20];
  const float* bv   = (const float*)d_in[21];
  const float* Wo   = (const float*)d_in[22];
  const float* bo   = (const float*)d_in[23];
  const float* W1   = (const float*)d_in[24];
  const float* b1   = (const float*)d_in[25];
  const float* gam  = (const float*)d_in[26];
  const float* bet  = (const float*)d_in[27];
  const float* W2   = (const float*)d_in[28];
  const float* b2   = (const float*)d_in[29];
  float* out = (float*)d_out;

  const int N = in_sizes[0]/DD;
  const int E = in_sizes[1]/2;
  const int B = out_size;
  const int J = in_sizes[25];
  (void)n_in; (void)ws_size;

  char* ws = (char*)d_ws;
  size_t off = 0;
  auto carve = [&](size_t bytes)->void*{ void* p = ws + off; off = (off + bytes + 255) & ~(size_t)255; return p; };
  float* hpA   = (float*)carve((size_t)N*DD*4);
  float* hlA   = (float*)carve((size_t)N*DD*4);
  float* hpB   = (float*)carve((size_t)N*DD*4);
  float* hlB   = (float*)carve((size_t)N*DD*4);
  float* dinvp = (float*)carve((size_t)N*4);
  float* dinvl = (float*)carve((size_t)N*4);
  int*   cnt   = (int*)  carve((size_t)N*4);
  unsigned int* packed = (unsigned int*)carve((size_t)N*4);
  int*   rowptr= (int*)  carve((size_t)(N+1)*4);
  int*   cursor= (int*)  carve((size_t)N*4);
  int*   bsum  = (int*)  carve(4096);
  int*   col   = (int*)  carve((size_t)E*4);
  float* coef  = (float*)carve((size_t)E*4);
  float* pro   = (float*)carve((size_t)B*DD*4);
  float* lig   = (float*)carve((size_t)B*DD*4);
  int*   bstart= (int*)  carve((size_t)B*4);
  int*   bend  = (int*)  carve((size_t)B*4);
  float* hbc   = (float*)carve((size_t)TT*DD*4);
  float* hbcst = (float*)carve(2*DD*4);
  float* outseq= (float*)carve((size_t)B*TT*DHX*4);
  float* PT    = (float*)carve((size_t)3*DHX*B*4);
  float* w1s   = (float*)carve((size_t)J*DHX*4);
  float* yT    = (float*)carve((size_t)J*B*4);

  int mx = (N>B)?N:B;
  k_init<<<(mx+255)/256, 256, 0, stream>>>(packed, bstart, bend, out, b2, N, B);
  k_edge_deg<<<(E+255)/256, 256, 0, stream>>>(ei, split, packed, E);
  k_node1<<<(N+255)/256, 256, 0, stream>>>(packed, dinvp, dinvl, cnt, batch, bstart, bend, N);
  int n4 = (N+3)/4;
  int nbA = (n4+255)/256;
  k_scanA<<<nbA, 256, 0, stream>>>(cnt, rowptr, bsum, N);
  k_scanB<<<1, 512, 0, stream>>>(bsum, nbA);
  k_scanC<<<(N+255)/256, 256, 0, stream>>>(rowptr, cursor, bsum, N, E);
  k_fill<<<(E+255)/256, 256, 0, stream>>>(ei, split, dinvp, dinvl, cursor, col, coef, E);

  const float* ip = x; const float* il = x;
  float* op_ = hpA; float* ol_ = hlA; float* np_ = hpB; float* nl_ = hlB;
  for (int i=0;i<5;++i){
    k_gcn<<<(N+3)/4, 256, 0, stream>>>(ip, il, op_, ol_, rowptr, col, coef, dinvp, dinvl,
      Wp + (size_t)i*DD*DD, bp + (size_t)i*DD, Wl + (size_t)i*DD*DD, bl + (size_t)i*DD, N);
    ip = op_; il = ol_;
    float* tp = op_; op_ = np_; np_ = tp;
    float* tl = ol_; ol_ = nl_; nl_ = tl;
  }

  k_bsum<<<B, 256, 0, stream>>>(ip, il, bstart, bend, pro, lig);
  k_lstm_common<<<1, 192, 0, stream>>>(wib, whb, bib, bhb, hbc, hbcst);
  k_lstm_batch<<<B, 192, 0, stream>>>(lig, pro, wif, whf, bif, bhf, wib, whb, bib, bhb, hbc, hbcst, outseq);
  k_attn<<<B, 256, 0, stream>>>(outseq, Wq, bq, Wk, bk, Wv, bv, Wo, bo, PT, B);
  k_w1s<<<J, 128, 0, stream>>>(W1, w1s);
  k_y<<<J, B, 0, stream>>>(PT, W1, w1s, b1, yT, B);
  k_bn<<<(J+31)/32, B, 0, stream>>>(yT, gam, bet, W2, out, B, J);
}

// Round 3
// 3826.752 us; speedup vs baseline: 2.3563x; 1.4467x over previous
//
#include <hip/hip_runtime.h>
#include <hip/hip_fp16.h>
#include <math.h>

#define DD 35
#define TT 140
#define DHX 70
#define GW 36   // padded fp16 row (35 + 1 pad), 72 bytes

__device__ __forceinline__ float sigf(float x){ return 1.0f/(1.0f+expf(-x)); }

// ---------------- init ----------------
__global__ void k_init(unsigned int* packed, int* bstart, int* bend,
                       float* out, const float* b2, int N, int B){
  int i = blockIdx.x*blockDim.x + threadIdx.x;
  if (i < N){ packed[i]=0u; }
  if (i < B){ bstart[i] = 0x7fffffff; bend[i] = 0; out[i] = b2[0]; }
}

// ---------------- degree count (packed: hi16=protein, lo16=ligand) ----------
__global__ void k_edge_deg(const int* __restrict__ ei, const int* __restrict__ split,
                           unsigned int* packed, int E){
  int e = blockIdx.x*blockDim.x + threadIdx.x;
  if (e >= E) return;
  int s = ei[e], d = ei[E+e];
  atomicAdd(&packed[d], (split[s]==1) ? 0x10000u : 1u);
}

// unpack degrees -> rsqrt; CSR counts; batch ranges via boundary detection
__global__ void k_node1(const unsigned int* __restrict__ packed,
                        float* dinvp, float* dinvl, int* cnt,
                        const int* __restrict__ batch,
                        int* bstart, int* bend, int N){
  int i = blockIdx.x*blockDim.x + threadIdx.x;
  if (i >= N) return;
  unsigned int p = packed[i];
  int pc = (int)(p >> 16), lc = (int)(p & 0xFFFFu);
  dinvp[i] = rsqrtf((float)(pc + 1));
  dinvl[i] = rsqrtf((float)(lc + 1));
  cnt[i] = pc + lc;
  int b = batch[i];
  if (i == 0 || batch[i-1] != b) bstart[b] = i;
  if (i == N-1 || batch[i+1] != b) bend[b] = i + 1;
}

// ---------------- exclusive scan (3 phase), 1024 elems / block ----------------
__global__ void k_scanA(const int* __restrict__ cnt, int* excl, int* bsum, int N){
  __shared__ int sh[256];
  int t = threadIdx.x;
  int base = (blockIdx.x*256 + t)*4;
  int v0 = (base+0<N)? cnt[base+0]:0;
  int v1 = (base+1<N)? cnt[base+1]:0;
  int v2 = (base+2<N)? cnt[base+2]:0;
  int v3 = (base+3<N)? cnt[base+3]:0;
  int s = v0+v1+v2+v3;
  sh[t] = s; __syncthreads();
  for (int o=1;o<256;o<<=1){
    int add = (t>=o)? sh[t-o] : 0; __syncthreads();
    sh[t] += add; __syncthreads();
  }
  int incl = sh[t];
  int ex = incl - s;
  if (t==255) bsum[blockIdx.x] = incl;
  if (base+0<N) excl[base+0]=ex;
  if (base+1<N) excl[base+1]=ex+v0;
  if (base+2<N) excl[base+2]=ex+v0+v1;
  if (base+3<N) excl[base+3]=ex+v0+v1+v2;
}

__global__ void k_scanB(int* bsum, int nb){
  __shared__ int sh[512];
  int t = threadIdx.x;
  int s = (t<nb)? bsum[t] : 0;
  sh[t]=s; __syncthreads();
  for (int o=1;o<512;o<<=1){
    int add=(t>=o)?sh[t-o]:0; __syncthreads();
    sh[t]+=add; __syncthreads();
  }
  if (t<nb) bsum[t] = sh[t]-s;
}

__global__ void k_scanC(int* rowptr, int* cursor, const int* __restrict__ bsum, int N, int E){
  int i = blockIdx.x*blockDim.x + threadIdx.x;
  if (i<N){ int v = rowptr[i] + bsum[i>>10]; rowptr[i]=v; cursor[i]=v; }
  if (i==0) rowptr[N] = E;
}

// ---------------- fill CSR: {src, +-dinv[src]} interleaved ----------------
__global__ void k_fill(const int* __restrict__ ei, const int* __restrict__ split,
                       const float* __restrict__ dinvp, const float* __restrict__ dinvl,
                       int* cursor, int2* ecs, int E){
  int e = blockIdx.x*blockDim.x + threadIdx.x;
  if (e >= E) return;
  int s = ei[e], d = ei[E+e];
  int pos = atomicAdd(&cursor[d], 1);
  float c = (split[s]==1) ? dinvp[s] : -dinvl[s];
  ecs[pos] = make_int2(s, __float_as_int(c));
}

// ---------------- pack x -> fp16 g0 ----------------
__global__ void k_pack0(const float* __restrict__ x, __half* __restrict__ g, int N){
  int i = blockIdx.x*blockDim.x + threadIdx.x;
  int node = i/18, p = i - node*18;
  if (node >= N) return;
  float h0 = x[(size_t)node*DD + 2*p];
  float h1 = (p==17)? 0.f : x[(size_t)node*DD + 2*p + 1];
  __half2 hh; hh.x = __float2half_rn(h0); hh.y = __float2half_rn(h1);
  *(__half2*)(g + (size_t)node*GW + 2*p) = hh;
}

// ---------------- fused GCN layer, fp16 pipeline, 3 edges/wave ----------------
__global__ void __launch_bounds__(256)
k_gcn(const __half* __restrict__ gp, const __half* __restrict__ gl,
      __half* __restrict__ gpo, __half* __restrict__ glo,
      const int* __restrict__ rowptr, const int2* __restrict__ ecs,
      const float* __restrict__ dinvp, const float* __restrict__ dinvl,
      const float* __restrict__ Wp, const float* __restrict__ bp,
      const float* __restrict__ Wl, const float* __restrict__ bl, int N){
  int node = blockIdx.x*4 + (threadIdx.x>>6);
  if (node >= N) return;
  int ln = threadIdx.x & 63;
  int grp = ln/18, sub = ln - grp*18;   // 3 active groups of 18 lanes; grp 3 idle
  bool gact = grp < 3;
  int e0 = rowptr[node], e1 = rowptr[node+1];
  float apx=0.f, apy=0.f, alx=0.f, aly=0.f;
  int e = e0;
  for (; e + 6 <= e1; e += 6){
    int i0 = e + grp, i1 = e + 3 + grp;
    int2 ec0 = gact ? ecs[i0] : make_int2(0,0);
    int2 ec1 = gact ? ecs[i1] : make_int2(0,0);
    float c0 = gact ? __int_as_float(ec0.y) : 0.f;
    float c1 = gact ? __int_as_float(ec1.y) : 0.f;
    const __half* b0 = (c0 > 0.f) ? gp : gl;
    const __half* b1 = (c1 > 0.f) ? gp : gl;
    __half2 u0{}, u1{};
    if (gact){
      u0 = *(const __half2*)(b0 + (size_t)ec0.x*GW + 2*sub);
      u1 = *(const __half2*)(b1 + (size_t)ec1.x*GW + 2*sub);
    }
    float2 h0 = __half22float2(u0);
    float2 h1 = __half22float2(u1);
    float cp0 = fmaxf(c0,0.f), cn0 = fmaxf(-c0,0.f);
    float cp1 = fmaxf(c1,0.f), cn1 = fmaxf(-c1,0.f);
    apx += cp0*h0.x + cp1*h1.x;  apy += cp0*h0.y + cp1*h1.y;
    alx += cn0*h0.x + cn1*h1.x;  aly += cn0*h0.y + cn1*h1.y;
  }
  for (; e < e1; e += 3){
    int idx = e + grp;
    bool ok = gact && (idx < e1);
    int2 ec = ok ? ecs[idx] : make_int2(0,0);
    float c = ok ? __int_as_float(ec.y) : 0.f;
    const __half* bb = (c > 0.f) ? gp : gl;
    __half2 u{};
    if (ok) u = *(const __half2*)(bb + (size_t)ec.x*GW + 2*sub);
    float2 h = __half22float2(u);
    float cp = fmaxf(c,0.f), cn = fmaxf(-c,0.f);
    apx += cp*h.x; apy += cp*h.y; alx += cn*h.x; aly += cn*h.y;
  }
  // reduce 3 groups -> lanes 0..17
  apx += __shfl(apx,(ln+18)&63,64) + __shfl(apx,(ln+36)&63,64);
  apy += __shfl(apy,(ln+18)&63,64) + __shfl(apy,(ln+36)&63,64);
  alx += __shfl(alx,(ln+18)&63,64) + __shfl(alx,(ln+36)&63,64);
  aly += __shfl(aly,(ln+18)&63,64) + __shfl(aly,(ln+36)&63,64);
  // self-loop + dinv[dst] factor, still packed (lanes 0..17)
  float dp = dinvp[node], dl = dinvl[node];
  __half2 sp2{}, sl2{};
  if (ln < 18){
    sp2 = *(const __half2*)(gp + (size_t)node*GW + 2*ln);
    sl2 = *(const __half2*)(gl + (size_t)node*GW + 2*ln);
  }
  float2 spf = __half22float2(sp2), slf = __half22float2(sl2);
  apx = dp*apx + spf.x*dp*dp;  apy = dp*apy + spf.y*dp*dp;
  alx = dl*alx + slf.x*dl*dl;  aly = dl*aly + slf.y*dl*dl;
  // redistribute packed(18x2) -> 35-lane layout
  int pr = ln>>1, odd = ln&1;
  float zpx = __shfl(apx, pr, 64), zpy = __shfl(apy, pr, 64);
  float zlx = __shfl(alx, pr, 64), zly = __shfl(aly, pr, 64);
  bool act = ln < DD;
  float zp = act ? (odd ? zpy : zpx) : 0.f;
  float zl = act ? (odd ? zly : zlx) : 0.f;
  // matvec via shfl broadcast
  float op = 0.f, ol = 0.f;
  for (int j=0;j<DD;++j){
    float zpj = __shfl(zp, j, 64);
    float zlj = __shfl(zl, j, 64);
    float wp = act ? Wp[j*DD+ln] : 0.f;
    float wl = act ? Wl[j*DD+ln] : 0.f;
    op += zpj*wp; ol += zlj*wl;
  }
  float opb = act ? fmaxf(op + bp[ln], 0.f) : 0.f;
  float olb = act ? fmaxf(ol + bl[ln], 0.f) : 0.f;
  // pack both stacks to fp16 out
  float p0 = __shfl(opb, (2*ln)&63, 64), p1 = __shfl(opb, (2*ln+1)&63, 64);
  float l0 = __shfl(olb, (2*ln)&63, 64), l1 = __shfl(olb, (2*ln+1)&63, 64);
  if (ln < 18){
    __half2 ap2; ap2.x = __float2half_rn(p0); ap2.y = __float2half_rn(p1);
    __half2 al2; al2.x = __float2half_rn(l0); al2.y = __float2half_rn(l1);
    *(__half2*)(gpo + (size_t)node*GW + 2*ln) = ap2;
    *(__half2*)(glo + (size_t)node*GW + 2*ln) = al2;
  }
}

// ---------------- batch pooling (fp16 in, f32 out) ----------------
__global__ void k_bsum(const __half* __restrict__ gp, const __half* __restrict__ gl,
                       const int* __restrict__ bstart, const int* __restrict__ bend,
                       float* pro, float* lig){
  __shared__ float sp[4][GW], sl[4][GW];
  int b = blockIdx.x;
  int w = threadIdx.x>>6, ln = threadIdx.x&63;
  int s0 = bstart[b], s1 = bend[b];
  float apx=0.f, apy=0.f, alx=0.f, aly=0.f;
  if (ln < 18){
    for (int n=s0+w; n<s1; n+=4){
      float2 a = __half22float2(*(const __half2*)(gp + (size_t)n*GW + 2*ln));
      float2 c = __half22float2(*(const __half2*)(gl + (size_t)n*GW + 2*ln));
      apx+=a.x; apy+=a.y; alx+=c.x; aly+=c.y;
    }
    sp[w][2*ln]=apx; sp[w][2*ln+1]=apy;
    sl[w][2*ln]=alx; sl[w][2*ln+1]=aly;
  }
  __syncthreads();
  if (threadIdx.x < DD){
    int d = threadIdx.x;
    pro[b*DD+d] = sp[0][d]+sp[1][d]+sp[2][d]+sp[3][d];
    lig[b*DD+d] = sl[0][d]+sl[1][d]+sl[2][d]+sl[3][d];
  }
}

// ---------------- reverse LSTM common chain (zero inputs, steps t=139..2) -------
__global__ void k_lstm_common(const float* __restrict__ wib, const float* __restrict__ whb,
                              const float* __restrict__ bib, const float* __restrict__ bhb,
                              float* hbc, float* hbcst){
  __shared__ float h[DD], cc[DD], g[4*DD];
  int t = threadIdx.x;
  if (t < DD){ h[t]=0.f; cc[t]=0.f; }
  __syncthreads();
  for (int k=1;k<=TT-2;++k){
    if (t < 4*DD){
      float acc = bib[t]+bhb[t];
      for (int m=0;m<DD;++m) acc += whb[t*DD+m]*h[m];
      g[t]=acc;
    }
    __syncthreads();
    if (t < DD){
      float ig=g[t], fg=g[DD+t], gg=g[2*DD+t], og=g[3*DD+t];
      float cv = sigf(fg)*cc[t] + sigf(ig)*tanhf(gg);
      float hv = sigf(og)*tanhf(cv);
      cc[t]=cv; h[t]=hv;
      hbc[(TT-k)*DD + t] = hv;
    }
    __syncthreads();
  }
  if (t<DD){ hbcst[t]=h[t]; hbcst[DD+t]=cc[t]; }
}

// ---------------- per-batch LSTM: fwd 140 steps + bwd 2-step tail ---------------
__global__ void k_lstm_batch(const float* __restrict__ lig, const float* __restrict__ pro,
   const float* __restrict__ wif, const float* __restrict__ whf,
   const float* __restrict__ bif, const float* __restrict__ bhf,
   const float* __restrict__ wib, const float* __restrict__ whb,
   const float* __restrict__ bib, const float* __restrict__ bhb,
   const float* __restrict__ hbc, const float* __restrict__ hbcst, float* outseq){
  __shared__ float x0[DD], x1[DD], h[DD], cc[DD], g[4*DD], xg0[4*DD], xg1[4*DD];
  int b = blockIdx.x, t = threadIdx.x;
  if (t<DD){ x0[t]=lig[b*DD+t]; x1[t]=pro[b*DD+t]; h[t]=0.f; cc[t]=0.f; }
  __syncthreads();
  if (t<4*DD){
    float a0=0.f, a1=0.f;
    for (int m=0;m<DD;++m){ a0 += wif[t*DD+m]*x0[m]; a1 += wif[t*DD+m]*x1[m]; }
    xg0[t]=a0; xg1[t]=a1;
  }
  __syncthreads();
  float* outb = outseq + (size_t)b*TT*DHX;
  for (int tt=0;tt<TT;++tt){
    if (t<4*DD){
      float acc = bif[t]+bhf[t] + (tt==0? xg0[t] : (tt==1? xg1[t] : 0.f));
      for (int m=0;m<DD;++m) acc += whf[t*DD+m]*h[m];
      g[t]=acc;
    }
    __syncthreads();
    if (t<DD){
      float ig=g[t], fg=g[DD+t], gg=g[2*DD+t], og=g[3*DD+t];
      float cv = sigf(fg)*cc[t]+sigf(ig)*tanhf(gg);
      float hv = sigf(og)*tanhf(cv);
      cc[t]=cv; h[t]=hv;
      outb[tt*DHX + t] = hv;
    }
    __syncthreads();
  }
  if (t<4*DD){
    float a0=0.f, a1=0.f;
    for (int m=0;m<DD;++m){ a0 += wib[t*DD+m]*x0[m]; a1 += wib[t*DD+m]*x1[m]; }
    xg0[t]=a0; xg1[t]=a1;
  }
  if (t<DD){ h[t]=hbcst[t]; cc[t]=hbcst[DD+t]; }
  __syncthreads();
  for (int step=0; step<2; ++step){
    int tt = 1-step;
    if (t<4*DD){
      float acc = bib[t]+bhb[t] + (tt==1? xg1[t] : xg0[t]);
      for (int m=0;m<DD;++m) acc += whb[t*DD+m]*h[m];
      g[t]=acc;
    }
    __syncthreads();
    if (t<DD){
      float ig=g[t], fg=g[DD+t], gg=g[2*DD+t], og=g[3*DD+t];
      float cv = sigf(fg)*cc[t]+sigf(ig)*tanhf(gg);
      float hv = sigf(og)*tanhf(cv);
      cc[t]=cv; h[t]=hv;
      outb[tt*DHX + DD + t] = hv;
    }
    __syncthreads();
  }
  for (int idx=t; idx<(TT-2)*DD; idx+=blockDim.x){
    int tt = 2 + idx/DD, d = idx%DD;
    outb[tt*DHX + DD + d] = hbc[tt*DD + d];
  }
}

// ---------------- attention (mask-collapsed) per batch ----------------
__global__ void __launch_bounds__(256)
k_attn(const float* __restrict__ outseq,
  const float* __restrict__ Wq, const float* __restrict__ bq,
  const float* __restrict__ Wk, const float* __restrict__ bk,
  const float* __restrict__ Wv, const float* __restrict__ bv,
  const float* __restrict__ Wo, const float* __restrict__ bo,
  float* PT, int B){
  __shared__ float so[TT*DHX];
  __shared__ float sk[TT*DHX];
  __shared__ float sv[TT*DHX];
  __shared__ float sq[2*DHX];
  __shared__ float es[TT];
  __shared__ float red[4];
  __shared__ float ctx[3*DHX];
  int b = blockIdx.x, tid = threadIdx.x;
  const float* ob = outseq + (size_t)b*TT*DHX;
  for (int i=tid;i<TT*DHX;i+=256) so[i]=ob[i];
  __syncthreads();
  for (int i=tid;i<TT*DHX;i+=256){
    int s=i/DHX, d=i%DHX;
    float ak=bk[d], av=bv[d];
    const float* r = so + s*DHX;
    for (int j=0;j<DHX;++j){ float o=r[j]; ak += o*Wk[d*DHX+j]; av += o*Wv[d*DHX+j]; }
    sk[i]=ak; sv[i]=av;
  }
  for (int i=tid;i<2*DHX;i+=256){
    int s=i/DHX, d=i%DHX;
    float a=bq[d];
    for (int j=0;j<DHX;++j) a += so[s*DHX+j]*Wq[d*DHX+j];
    sq[i]=a;
  }
  __syncthreads();
  const float scale = 0.11952286093343936f;
  for (int s=tid;s<TT;s+=256){
    float a=0.f;
    for (int j=0;j<DHX;++j) a += sq[DHX+j]*sk[s*DHX+j];
    es[s] = a*scale;
  }
  __syncthreads();
  if (tid < 64){
    float m=-1e30f;
    for (int s=tid;s<TT;s+=64) if (s!=1) m=fmaxf(m, es[s]);
    for (int o=32;o;o>>=1) m = fmaxf(m, __shfl_xor(m,o,64));
    if (tid==0) red[0]=m;
  }
  __syncthreads();
  float m = red[0];
  for (int s=tid;s<TT;s+=256) es[s] = (s==1)? 0.f : expf(es[s]-m);
  __syncthreads();
  if (tid<64){
    float sum=0.f;
    for (int s=tid;s<TT;s+=64) sum+=es[s];
    for (int o=32;o;o>>=1) sum += __shfl_xor(sum,o,64);
    if (tid==0) red[1]=sum;
  }
  if (tid==0){
    float s00=0.f,s01=0.f;
    for (int j=0;j<DHX;++j){ s00 += sq[j]*sk[j]; s01 += sq[j]*sk[DHX+j]; }
    s00*=scale; s01*=scale;
    float mm=fmaxf(s00,s01);
    float e0=expf(s00-mm), e1=expf(s01-mm);
    red[2]=e0/(e0+e1); red[3]=e1/(e0+e1);
  }
  __syncthreads();
  float inv = 1.0f/red[1];
  float a0=red[2], a1=red[3];
  if (tid < DHX){
    int d=tid;
    float c1=0.f;
    for (int s=0;s<TT;++s) c1 += es[s]*sv[s*DHX+d];
    ctx[DHX+d] = c1*inv;
    ctx[d] = a0*sv[d] + a1*sv[DHX+d];
    ctx[2*DHX+d] = sv[DHX+d];
  }
  __syncthreads();
  for (int i=tid;i<3*DHX;i+=256){
    int tt=i/DHX, d=i%DHX;
    float a=bo[d];
    const float* cv = ctx + tt*DHX;
    for (int j=0;j<DHX;++j) a += Wo[d*DHX+j]*cv[j];
    PT[(size_t)i*B + b] = a;
  }
}

// ---------------- W1 tail-block sum ----------------
__global__ void k_w1s(const float* __restrict__ W1, float* w1s){
  int j = blockIdx.x; int d = threadIdx.x;
  if (d >= DHX) return;
  const float* r = W1 + (size_t)j*(TT*DHX);
  float acc=0.f;
  for (int t=2;t<TT;++t) acc += r[t*DHX+d];
  w1s[(size_t)j*DHX+d]=acc;
}

// ---------------- y = P @ [W1a|W1b|W1s]^T + b1 ----------------
__global__ void k_y(const float* __restrict__ PT, const float* __restrict__ W1,
                    const float* __restrict__ w1s, const float* __restrict__ b1,
                    float* yT, int B){
  int j = blockIdx.x; int b = threadIdx.x;
  const float* r = W1 + (size_t)j*(TT*DHX);
  float acc = b1[j];
  for (int i=0;i<2*DHX;++i) acc += r[i]*PT[(size_t)i*B+b];
  const float* rs = w1s + (size_t)j*DHX;
  for (int i=0;i<DHX;++i) acc += rs[i]*PT[(size_t)(2*DHX+i)*B+b];
  yT[(size_t)j*B+b] = acc;
}

// ---------------- BatchNorm(train) + Mish + W2 reduce ----------------
__global__ void k_bn(const float* __restrict__ yT, const float* __restrict__ gamma,
                     const float* __restrict__ beta, const float* __restrict__ W2,
                     float* out, int B, int J){
  __shared__ float red_s[2];
  int b = threadIdx.x;
  int lane = b & 63, w = b>>6;
  float acc = 0.f;
  int j0 = blockIdx.x*32;
  float invB = 1.0f/(float)B;
  for (int jj=0;jj<32;++jj){
    int j = j0+jj; if (j>=J) break;
    float v = yT[(size_t)j*B + b];
    float s=v;
    for (int o=32;o;o>>=1) s += __shfl_xor(s,o,64);
    if (lane==0) red_s[w]=s;
    __syncthreads();
    float mu = (red_s[0]+red_s[1]) * invB;
    __syncthreads();
    float dd = v-mu;
    float q=dd*dd;
    for (int o=32;o;o>>=1) q += __shfl_xor(q,o,64);
    if (lane==0) red_s[w]=q;
    __syncthreads();
    float var = (red_s[0]+red_s[1]) * invB;
    __syncthreads();
    float xn = dd*rsqrtf(var+1e-5f)*gamma[j]+beta[j];
    float sp = (xn>20.f)? xn : log1pf(expf(xn));
    float mish = xn*tanhf(sp);
    acc += mish*W2[j];
  }
  atomicAdd(&out[b], acc);
}

extern "C" void kernel_launch(void* const* d_in, const int* in_sizes, int n_in,
                              void* d_out, int out_size, void* d_ws, size_t ws_size,
                              hipStream_t stream)
{
  const float* x    = (const float*)d_in[0];
  const int*   ei   = (const int*)  d_in[1];
  const int*   split= (const int*)  d_in[2];
  const int*   batch= (const int*)  d_in[3];
  const float* Wp   = (const float*)d_in[4];
  const float* bp   = (const float*)d_in[5];
  const float* Wl   = (const float*)d_in[6];
  const float* bl   = (const float*)d_in[7];
  const float* wif  = (const float*)d_in[8];
  const float* whf  = (const float*)d_in[9];
  const float* bif  = (const float*)d_in[10];
  const float* bhf  = (const float*)d_in[11];
  const float* wib  = (const float*)d_in[12];
  const float* whb  = (const float*)d_in[13];
  const float* bib  = (const float*)d_in[14];
  const float* bhb  = (const float*)d_in[15];
  const float* Wq   = (const float*)d_in[16];
  const float* bq   = (const float*)d_in[17];
  const float* Wk   = (const float*)d_in[18];
  const float* bk   = (const float*)d_in[19];
  const float* Wv   = (const float*)d_in[20];
  const float* bv   = (const float*)d_in[21];
  const float* Wo   = (const float*)d_in[22];
  const float* bo   = (const float*)d_in[23];
  const float* W1   = (const float*)d_in[24];
  const float* b1   = (const float*)d_in[25];
  const float* gam  = (const float*)d_in[26];
  const float* bet  = (const float*)d_in[27];
  const float* W2   = (const float*)d_in[28];
  const float* b2   = (const float*)d_in[29];
  float* out = (float*)d_out;

  const int N = in_sizes[0]/DD;
  const int E = in_sizes[1]/2;
  const int B = out_size;
  const int J = in_sizes[25];
  (void)n_in; (void)ws_size;

  char* ws = (char*)d_ws;
  size_t off = 0;
  auto carve = [&](size_t bytes)->void*{ void* p = ws + off; off = (off + bytes + 255) & ~(size_t)255; return p; };
  __half* g0   = (__half*)carve((size_t)N*GW*2);
  __half* gpA  = (__half*)carve((size_t)N*GW*2);
  __half* glA  = (__half*)carve((size_t)N*GW*2);
  __half* gpB  = (__half*)carve((size_t)N*GW*2);
  __half* glB  = (__half*)carve((size_t)N*GW*2);
  float* dinvp = (float*)carve((size_t)N*4);
  float* dinvl = (float*)carve((size_t)N*4);
  int*   cnt   = (int*)  carve((size_t)N*4);
  unsigned int* packed = (unsigned int*)carve((size_t)N*4);
  int*   rowptr= (int*)  carve((size_t)(N+1)*4);
  int*   cursor= (int*)  carve((size_t)N*4);
  int*   bsum  = (int*)  carve(4096);
  int2*  ecs   = (int2*) carve((size_t)E*8);
  float* pro   = (float*)carve((size_t)B*DD*4);
  float* lig   = (float*)carve((size_t)B*DD*4);
  int*   bstart= (int*)  carve((size_t)B*4);
  int*   bend  = (int*)  carve((size_t)B*4);
  float* hbc   = (float*)carve((size_t)TT*DD*4);
  float* hbcst = (float*)carve(2*DD*4);
  float* outseq= (float*)carve((size_t)B*TT*DHX*4);
  float* PT    = (float*)carve((size_t)3*DHX*B*4);
  float* w1s   = (float*)carve((size_t)J*DHX*4);
  float* yT    = (float*)carve((size_t)J*B*4);

  int mx = (N>B)?N:B;
  k_init<<<(mx+255)/256, 256, 0, stream>>>(packed, bstart, bend, out, b2, N, B);
  k_edge_deg<<<(E+255)/256, 256, 0, stream>>>(ei, split, packed, E);
  k_node1<<<(N+255)/256, 256, 0, stream>>>(packed, dinvp, dinvl, cnt, batch, bstart, bend, N);
  int n4 = (N+3)/4;
  int nbA = (n4+255)/256;
  k_scanA<<<nbA, 256, 0, stream>>>(cnt, rowptr, bsum, N);
  k_scanB<<<1, 512, 0, stream>>>(bsum, nbA);
  k_scanC<<<(N+255)/256, 256, 0, stream>>>(rowptr, cursor, bsum, N, E);
  k_fill<<<(E+255)/256, 256, 0, stream>>>(ei, split, dinvp, dinvl, cursor, ecs, E);
  k_pack0<<<((size_t)N*18+255)/256, 256, 0, stream>>>(x, g0, N);

  const __half* gpi = g0; const __half* gli = g0;
  __half* gpo = gpA; __half* glo = glA; __half* gpn = gpB; __half* gln = glB;
  for (int i=0;i<5;++i){
    k_gcn<<<(N+3)/4, 256, 0, stream>>>(gpi, gli, gpo, glo, rowptr, ecs, dinvp, dinvl,
      Wp + (size_t)i*DD*DD, bp + (size_t)i*DD, Wl + (size_t)i*DD*DD, bl + (size_t)i*DD, N);
    gpi = gpo; gli = glo;
    __half* t1 = gpo; gpo = gpn; gpn = t1;
    __half* t2 = glo; glo = gln; gln = t2;
  }

  k_bsum<<<B, 256, 0, stream>>>(gpi, gli, bstart, bend, pro, lig);
  k_lstm_common<<<1, 192, 0, stream>>>(wib, whb, bib, bhb, hbc, hbcst);
  k_lstm_batch<<<B, 192, 0, stream>>>(lig, pro, wif, whf, bif, bhf, wib, whb, bib, bhb, hbc, hbcst, outseq);
  k_attn<<<B, 256, 0, stream>>>(outseq, Wq, bq, Wk, bk, Wv, bv, Wo, bo, PT, B);
  k_w1s<<<J, 128, 0, stream>>>(W1, w1s);
  k_y<<<J, B, 0, stream>>>(PT, W1, w1s, b1, yT, B);
  k_bn<<<(J+31)/32, B, 0, stream>>>(yT, gam, bet, W2, out, B, J);
}